// Round 12
// baseline (306.440 us; speedup 1.0000x reference)
//
#include <hip/hip_runtime.h>

#define N_NODES 100000
#define N_PAD 100032      // padded to 64-node tiles for MFMA sizematch
#define N_EDGES 1600000
#define NUM_RELS 8
#define KDIM 256      // E_DIM * MAX_LEN
#define HD 64
#define KF 512        // fused GEMM K = NUM_RELS * 64

// CSR-build partition parameters: 256-node coarse buckets
#define B_SHIFT 8
#define NBUCK 392         // ceil(100000/256)=391, +1 pad
#define NBUCK_USED 391
#define NBLK_P 512
#define TPB_P 256
#define EPB 3125          // 512 * 3125 = 1.6M exactly
#define NBLK_SM 1563      // N_PAD / 64

typedef __attribute__((ext_vector_type(8))) short bf16x8;
typedef __attribute__((ext_vector_type(4))) float f32x4;

// plain-POD edge pair for constant-addrspace scalar loads
struct EP { int x, y; };
typedef const __attribute__((address_space(4))) EP*  ep_cptr;
typedef const __attribute__((address_space(4))) int* ci_cptr;

__device__ inline unsigned short f2bf(float f) {
    unsigned u = __float_as_uint(f);
    u += 0x7fff + ((u >> 16) & 1);   // round-to-nearest-even
    return (unsigned short)(u >> 16);
}
__device__ inline float bf2f(unsigned short s) {
    return __uint_as_float(((unsigned)s) << 16);
}

// ---------------- build1: prep (packed weights + smPack + bf16 emb) ∥ pcount
// blocks [0, NBLK_P): per-block LDS histogram of dst -> global atomicAdd btot
// blocks [NBLK_P, ...): prep tasks by flat index
__launch_bounds__(256)
__global__ void k_build1(const float* __restrict__ V1, const float* __restrict__ comp1,
                         const float* __restrict__ V2, const float* __restrict__ comp2,
                         const float* __restrict__ sm_w, const float* __restrict__ emb_w,
                         const int* __restrict__ dst,
                         unsigned short* __restrict__ WpF1, unsigned short* __restrict__ WpF2,
                         unsigned short* __restrict__ smPack, unsigned* __restrict__ emb_bf,
                         int* __restrict__ btot) {
    __shared__ int lh[NBUCK];
    int t = threadIdx.x;
    if (blockIdx.x < NBLK_P) {
        int blk = blockIdx.x;
        for (int b = t; b < NBUCK; b += TPB_P) lh[b] = 0;
        __syncthreads();
        int base = blk * EPB;
        for (int i = t; i < EPB; i += TPB_P) atomicAdd(&lh[dst[base + i] >> B_SHIFT], 1);
        __syncthreads();
        for (int b = t; b < NBUCK; b += TPB_P) {
            int c = lh[b];
            if (c) atomicAdd(&btot[b], c);
        }
        return;
    }
    int idx = (blockIdx.x - NBLK_P) * 256 + t;
    if (idx < 65536) {
        int l = idx >> 15;
        int r = (idx >> 12) & 7;
        int k = (idx >> 6) & 63;
        int o = idx & 63;
        const float* V = l ? V2 : V1;
        const float* comp = l ? comp2 : comp1;
        float s = 0.f;
#pragma unroll
        for (int b = 0; b < 8; b++) s += comp[r * 8 + b] * V[(b * 64 + k) * 64 + o];
        int kk = r * 64 + k;
        int ss = kk >> 5, q = (kk >> 3) & 3, j = kk & 7;
        unsigned short* Wp = l ? WpF2 : WpF1;
        Wp[(((ss * 4 + q) * 64) + o) * 8 + j] = f2bf(s);
    } else if (idx < 81920) {
        int j = idx - 65536;
        int k = j >> 6, o = j & 63;
        int s = k >> 5, q = (k >> 3) & 3, jj = k & 7;
        smPack[(((s * 4 + q) * 64) + o) * 8 + jj] = f2bf(sm_w[o * KDIM + k]);
    } else {
        int j = idx - 81920;                 // pair index: 3.2M bf16 = 1.6M dwords
        if (j < 1600000) {
            const float2* f2p = (const float2*)emb_w;
            float2 f = f2p[j];
            emb_bf[j] = ((unsigned)f2bf(f.x)) | (((unsigned)f2bf(f.y)) << 16);
        }
    }
}

// ---------------- scan0: 1-block exclusive scan of btot -> bstart, wpos; sentinel
__launch_bounds__(512)
__global__ void k_scan0(const int* __restrict__ btot, int* __restrict__ bstart,
                        int* __restrict__ wpos, int* __restrict__ rowptr8) {
    __shared__ int s[512];
    int t = threadIdx.x;
    int v = (t < NBUCK_USED) ? btot[t] : 0;
    s[t] = v;
    __syncthreads();
    for (int off = 1; off < 512; off <<= 1) {
        int u = (t >= off) ? s[t - off] : 0;
        __syncthreads();
        s[t] += u;
        __syncthreads();
    }
    int excl = s[t] - v;
    if (t < NBUCK) { bstart[t] = excl; wpos[t] = excl; }
    if (t == 0) rowptr8[(size_t)N_NODES * 8] = N_EDGES;
}

// ---------------- build2: pscatter (dynamic bucket reservations) ∥ sizematch
// blocks [0, NBLK_P): pass1 LDS histogram of this block's edges; per-bucket
//   global reservation lh[b] = atomicAdd(&wpos[b], lh[b]); pass2 scatter via
//   LDS cursors. Same per-block-contiguous write locality as the old boffm
//   path; within-bucket order is arbitrary (consume is order-free).
// blocks [NBLK_P, NBLK_P+NBLK_SM): size matcher (MFMA, bf16 emb 64 B/row)
__launch_bounds__(256)
__global__ void k_build2(const int* __restrict__ src, const int* __restrict__ dst,
                         const int* __restrict__ et, const float* __restrict__ norm,
                         int* __restrict__ wpos, int2* __restrict__ staged,
                         const int* __restrict__ feat, const unsigned* __restrict__ emb_bf,
                         const unsigned short* __restrict__ smPack, const float* __restrict__ sm_b,
                         unsigned short* __restrict__ xb) {
    __shared__ int lh[NBUCK];
    int t = threadIdx.x;
    if (blockIdx.x < NBLK_P) {
        int blk = blockIdx.x;
        for (int b = t; b < NBUCK; b += TPB_P) lh[b] = 0;
        __syncthreads();
        int base = blk * EPB;
        for (int i = t; i < EPB; i += TPB_P) atomicAdd(&lh[dst[base + i] >> B_SHIFT], 1);
        __syncthreads();
        for (int b = t; b < NBUCK; b += TPB_P) {
            int c = lh[b];
            if (c) lh[b] = atomicAdd(&wpos[b], c);   // reserve contiguous range
        }
        __syncthreads();
        for (int i = t; i < EPB; i += TPB_P) {
            int e = base + i;
            int d = dst[e];
            int bu = d >> B_SHIFT;
            int pos = atomicAdd(&lh[bu], 1);
            int packed = src[e] | (et[e] << 17) | ((d & 255) << 20);
            staged[pos] = make_int2(packed, __float_as_int(norm[e]));
        }
        return;
    }
    // ---- size matcher
    int wave = t >> 6, lane = t & 63;
    int q = lane >> 4, c = lane & 15;
    int n0 = (blockIdx.x - NBLK_P) * 64 + wave * 16;
    int node = n0 + c;
    int nclamp = (node < N_NODES) ? node : (N_NODES - 1);
    const int4* fr = (const int4*)(feat + (size_t)nclamp * 8);
    int4 f0 = fr[0], f1 = fr[1];
    int fidx[8] = {f0.x, f0.y, f0.z, f0.w, f1.x, f1.y, f1.z, f1.w};
    f32x4 acc[4];
#pragma unroll
    for (int i = 0; i < 4; i++) acc[i] = (f32x4){0.f, 0.f, 0.f, 0.f};
    const bf16x8* B8 = (const bf16x8*)smPack;
#pragma unroll
    for (int s = 0; s < 8; s++) {
        // row fidx[s] = 32 bf16 = 64 B; lane q takes elements q*8..q*8+7 (16 B)
        const int4* ar = (const int4*)((const char*)emb_bf + (size_t)fidx[s] * 64);
        union { int4 i; bf16x8 v; } A;
        A.i = ar[q];
#pragma unroll
        for (int tl = 0; tl < 4; tl++) {
            bf16x8 b = B8[(s * 4 + q) * 64 + tl * 16 + c];
            acc[tl] = __builtin_amdgcn_mfma_f32_16x16x32_bf16(A.v, b, acc[tl], 0, 0, 0);
        }
    }
    int row_base = n0 + q * 4;
    bool full = (n0 + 15 < N_NODES);
#pragma unroll
    for (int tl = 0; tl < 4; tl++) {
        int o = tl * 16 + c;
        float bia = sm_b[o];
#pragma unroll
        for (int r = 0; r < 4; r++) {
            int nd = row_base + r;
            if (full || nd < N_NODES)
                xb[(size_t)nd * 64 + o] = f2bf(acc[tl][r] + bia);
        }
    }
}

// ---------------- pass D: per-bucket 2048-bin counting sort -> rowptr8 + sorted edata
// bucket base/count read directly from bstart/btot (no scan preamble)
// edata stores x = (src<<7) | et  (byte offset of xin row in bits 7..23, rel in 0..2)
__launch_bounds__(512)
__global__ void k_finalize(const int2* __restrict__ staged, const int* __restrict__ bstart,
                           const int* __restrict__ btot,
                           int* __restrict__ rowptr8, int2* __restrict__ edata) {
    __shared__ int lh[2048];
    __shared__ int s512[512];
    __shared__ int lsc[2048];
    int b = blockIdx.x, t = threadIdx.x;
    int base = bstart[b];
    int cnt = btot[b];
    lh[t] = 0; lh[t + 512] = 0; lh[t + 1024] = 0; lh[t + 1536] = 0;
    __syncthreads();
    int2 held[9];
    int key[9], rank[9];
    int nh = 0;
    for (int i = t; i < cnt; i += 512) {
        int2 ed = staged[base + i];
        int k = (ed.x >> 17) & 2047;
        held[nh] = ed; key[nh] = k; rank[nh] = atomicAdd(&lh[k], 1); nh++;
    }
    __syncthreads();
    int b0 = lh[t * 4], b1 = lh[t * 4 + 1], b2 = lh[t * 4 + 2], b3 = lh[t * 4 + 3];
    int tot = b0 + b1 + b2 + b3;
    s512[t] = tot;
    __syncthreads();
    for (int off = 1; off < 512; off <<= 1) {
        int u = (t >= off) ? s512[t - off] : 0;
        __syncthreads();
        s512[t] += u;
        __syncthreads();
    }
    int excl = s512[t] - tot;
    lsc[t * 4] = excl;
    lsc[t * 4 + 1] = excl + b0;
    lsc[t * 4 + 2] = excl + b0 + b1;
    lsc[t * 4 + 3] = excl + b0 + b1 + b2;
    __syncthreads();
    int limit = (N_NODES << 3) - (b << 11);
    for (int idx = t; idx < 2048; idx += 512)
        if (idx < limit) rowptr8[(b << 11) + idx] = base + lsc[idx];
    for (int i = 0; i < nh; i++) {
        int p = base + lsc[key[i]] + rank[i];
        int srcv = held[i].x & 0x1FFFF;
        int etv  = (held[i].x >> 17) & 7;
        edata[p] = make_int2((srcv << 7) | etv, held[i].y);   // byte-offset | et
    }
}

// ---------------- fused layer: branchless always-write aggregation + MFMA (R5/R8)
// block: 256 thr = 4 waves; 16 nodes/block (4 per wave); grid N_NODES/16.
// Edge descriptors via addrspace(4) scalar loads (s_load into SGPRs).
// Consume is BRANCHLESS: keep = (et==prev), acc = fma(y,w, acc*keep), and the
// running sum is stored to agg[row][et*64+lane] EVERY edge (shift-16 store).
// The last write of each rel segment leaves the final value.
// NOTE: no min-waves hint — forcing 8 blocks/CU (R9) raised occupancy 59->69%
// but thrashed L2 on the xin gathers (FETCH 93->109 MB) and cost +6.5 us.
__launch_bounds__(256)
__global__ void k_fused(const unsigned short* __restrict__ xin,
                        const int* __restrict__ rowptr8, const int2* __restrict__ edata,
                        const unsigned short* __restrict__ WpF, const float* __restrict__ bias,
                        float* __restrict__ outf, unsigned short* __restrict__ outb, int mode) {
    __shared__ __align__(16) unsigned short agg[16 * 520];
    int t = threadIdx.x;
    int wave = t >> 6, lane = t & 63;
    int n0 = blockIdx.x * 16;
    ep_cptr ep4 = (ep_cptr)(unsigned long long)edata;
    ci_cptr rp4 = (ci_cptr)(unsigned long long)rowptr8;
    // each wave zero-inits only its OWN 4 rows; it is also the only writer of
    // them during the edge phase, so no barrier is needed before the edge loop.
    {
        int* a4 = (int*)agg + wave * 4 * 260;
        for (int i = lane; i < 4 * 260; i += 64) a4[i] = 0;
    }
#define EF(S,k)  int x##S##k = ep4[j##S + (k)].x, y##S##k = ep4[j##S + (k)].y;
#define EFM(S,k) int q##S##k = j##S + (k); \
                 int c##S##k = (q##S##k <= last##S) ? q##S##k : last##S; \
                 c##S##k = (c##S##k < 0) ? 0 : c##S##k; \
                 int x##S##k = ep4[c##S##k].x; \
                 int y##S##k = (q##S##k <= last##S) ? ep4[c##S##k].y : 0;
#define GF(S,k)  unsigned short w##S##k = *((const unsigned short*)((const char*)xin + (x##S##k & 0x00FFFF80)) + lane);
#define CN(S,k)  { int et = x##S##k & 7; \
                   float keep = (et == prev##S) ? 1.0f : 0.0f; \
                   prev##S = et; \
                   acc##S = fmaf(__int_as_float(y##S##k), bf2f(w##S##k), acc##S * keep); \
                   unsigned bb = __float_as_uint(acc##S) + 0x8000u; \
                   aggrow##S[et * 64 + lane] = (unsigned short)(bb >> 16); }
#define EF8(S)   EF(S,0) EF(S,1) EF(S,2) EF(S,3) EF(S,4) EF(S,5) EF(S,6) EF(S,7)
#define EFM8(S)  EFM(S,0) EFM(S,1) EFM(S,2) EFM(S,3) EFM(S,4) EFM(S,5) EFM(S,6) EFM(S,7)
#define GF8(S)   GF(S,0) GF(S,1) GF(S,2) GF(S,3) GF(S,4) GF(S,5) GF(S,6) GF(S,7)
#define CN8(S)   CN(S,0) CN(S,1) CN(S,2) CN(S,3) CN(S,4) CN(S,5) CN(S,6) CN(S,7)
    for (int np = 0; np < 2; np++) {
        int lrowA = wave * 4 + np * 2;
        int lrowB = lrowA + 1;
        int nA = __builtin_amdgcn_readfirstlane(n0 + lrowA);
        int nB = nA + 1;
        int j0A = rp4[(size_t)nA * 8], j1A = rp4[(size_t)nA * 8 + 8];
        int j0B = rp4[(size_t)nB * 8], j1B = rp4[(size_t)nB * 8 + 8];
        unsigned short* aggrowA = agg + lrowA * 520;
        unsigned short* aggrowB = agg + lrowB * 520;
        float accA = 0.f, accB = 0.f;
        int prevA = -1, prevB = -1;
        int jA = j0A, jB = j0B;
        while (jA + 8 <= j1A && jB + 8 <= j1B) {
            EF8(A) EF8(B) GF8(A) GF8(B) CN8(A) CN8(B)
            jA += 8; jB += 8;
        }
        while (jA + 8 <= j1A) { EF8(A) GF8(A) CN8(A) jA += 8; }
        while (jB + 8 <= j1B) { EF8(B) GF8(B) CN8(B) jB += 8; }
        {
            int lastA = j1A - 1, lastB = j1B - 1;
            if (((j1A - jA) | (j1B - jB)) > 0) {
                EFM8(A) EFM8(B) GF8(A) GF8(B) CN8(A) CN8(B)
            }
        }
    }
#undef EF
#undef EFM
#undef GF
#undef CN
#undef EF8
#undef EFM8
#undef GF8
#undef CN8
    __syncthreads();
    // ---- MFMA: [16 nodes x 512] @ WpF -> 64 outs; wave covers cols [wave*16, +16)
    int q = lane >> 4, c = lane & 15;
    int o16 = wave * 16;
    f32x4 accd = (f32x4){0.f, 0.f, 0.f, 0.f};
    const bf16x8* B8 = (const bf16x8*)WpF;
#pragma unroll
    for (int s = 0; s < 16; s++) {
        bf16x8 a = *(const bf16x8*)&agg[c * 520 + s * 32 + q * 8];
        bf16x8 bfr = B8[(s * 4 + q) * 64 + o16 + c];
        accd = __builtin_amdgcn_mfma_f32_16x16x32_bf16(a, bfr, accd, 0, 0, 0);
    }
    int col = o16 + c;
    float bia = bias[col];
#pragma unroll
    for (int r = 0; r < 4; r++) {
        int node = n0 + q * 4 + r;
        float v = accd[r] + bia;
        if (mode == 1) {
            v = fmaxf(v, 0.f);
            outb[(size_t)node * 64 + col] = f2bf(v);
        } else {
            outf[(size_t)node * 64 + col] = v;
        }
    }
}

extern "C" void kernel_launch(void* const* d_in, const int* in_sizes, int n_in,
                              void* d_out, int out_size, void* d_ws, size_t ws_size,
                              hipStream_t stream) {
    const int*   feat  = (const int*)d_in[0];
    const int*   src   = (const int*)d_in[1];
    const int*   dst   = (const int*)d_in[2];
    const int*   etype = (const int*)d_in[3];
    const float* norm  = (const float*)d_in[4];
    const float* emb_w = (const float*)d_in[5];
    const float* sm_w  = (const float*)d_in[6];
    const float* sm_b  = (const float*)d_in[7];
    const float* V1    = (const float*)d_in[8];
    const float* comp1 = (const float*)d_in[9];
    const float* b1    = (const float*)d_in[10];
    const float* V2    = (const float*)d_in[11];
    const float* comp2 = (const float*)d_in[12];
    const float* b2    = (const float*)d_in[13];
    float* out = (float*)d_out;

    char* p = (char*)d_ws;
    auto alloc = [&](size_t bytes) { void* q = (void*)p; p += (bytes + 255) & ~(size_t)255; return q; };
    unsigned short* xb     = (unsigned short*)alloc((size_t)N_PAD * 64 * 2);   // 12.8 MB
    unsigned short* hb     = (unsigned short*)alloc((size_t)N_PAD * 64 * 2);   // 12.8 MB
    unsigned short* WpF1   = (unsigned short*)alloc((size_t)KF * HD * 2);      // 64 KB
    unsigned short* WpF2   = (unsigned short*)alloc((size_t)KF * HD * 2);
    unsigned short* smPack = (unsigned short*)alloc(KDIM * HD * 2);            // 32 KB
    unsigned*       emb_bf = (unsigned*)alloc((size_t)N_NODES * 32 * 2);       // 6.4 MB
    int*   btot   = (int*)alloc((size_t)NBUCK * 4);
    int*   bstart = (int*)alloc((size_t)(NBUCK + 1) * 4);
    int*   wpos   = (int*)alloc((size_t)NBUCK * 4);
    int*   rowptr8 = (int*)alloc(((size_t)N_NODES * 8 + 1) * 4);               // 3.2 MB
    int2*  staged = (int2*)alloc((size_t)N_EDGES * 8);                         // 12.8 MB
    int2*  edata  = (int2*)alloc((size_t)N_EDGES * 8);                         // 12.8 MB

    hipMemsetAsync(btot, 0, (size_t)NBUCK * 4, stream);

    // build1: 512 pcount blocks + 6570 prep blocks
    k_build1<<<NBLK_P + 6570, 256, 0, stream>>>(V1, comp1, V2, comp2, sm_w, emb_w, dst,
                                                WpF1, WpF2, smPack, emb_bf, btot);
    k_scan0<<<1, 512, 0, stream>>>(btot, bstart, wpos, rowptr8);
    // build2: 512 pscatter blocks + 1563 sizematch blocks
    k_build2<<<NBLK_P + NBLK_SM, 256, 0, stream>>>(src, dst, etype, norm, wpos, staged,
                                                   feat, emb_bf, smPack, sm_b, xb);
    k_finalize<<<NBUCK_USED, 512, 0, stream>>>(staged, bstart, btot, rowptr8, edata);

    k_fused<<<N_NODES / 16, 256, 0, stream>>>(xb, rowptr8, edata, WpF1, b1, nullptr, hb, 1);
    k_fused<<<N_NODES / 16, 256, 0, stream>>>(hb, rowptr8, edata, WpF2, b2, out, nullptr, 0);
}

// Round 13
// 288.099 us; speedup vs baseline: 1.0637x; 1.0637x over previous
//
#include <hip/hip_runtime.h>

#define N_NODES 100000
#define N_PAD 100032      // padded to 64-node tiles for MFMA sizematch
#define N_EDGES 1600000
#define NUM_RELS 8
#define KDIM 256      // E_DIM * MAX_LEN
#define HD 64
#define KF 512        // fused GEMM K = NUM_RELS * 64

// CSR-build partition parameters: 256-node coarse buckets
#define B_SHIFT 8
#define NBUCK 392         // ceil(100000/256)=391, +1 pad
#define NBUCK_USED 391
#define NBLK_P 512
#define TPB_P 256
#define EPB 3125          // 512 * 3125 = 1.6M exactly
#define NBLK_SM 1563      // N_PAD / 64

typedef __attribute__((ext_vector_type(8))) short bf16x8;
typedef __attribute__((ext_vector_type(4))) float f32x4;

// plain-POD edge pair for constant-addrspace scalar loads
struct EP { int x, y; };
typedef const __attribute__((address_space(4))) EP*  ep_cptr;
typedef const __attribute__((address_space(4))) int* ci_cptr;

__device__ inline unsigned short f2bf(float f) {
    unsigned u = __float_as_uint(f);
    u += 0x7fff + ((u >> 16) & 1);   // round-to-nearest-even
    return (unsigned short)(u >> 16);
}
__device__ inline float bf2f(unsigned short s) {
    return __uint_as_float(((unsigned)s) << 16);
}

// ---------------- build1: prep (packed weights + smPack + bf16 emb) ∥ pcount
// blocks [0, NBLK_P): per-block LDS histogram of dst over coarse buckets
// blocks [NBLK_P, ...): prep tasks by flat index
__launch_bounds__(256)
__global__ void k_build1(const float* __restrict__ V1, const float* __restrict__ comp1,
                         const float* __restrict__ V2, const float* __restrict__ comp2,
                         const float* __restrict__ sm_w, const float* __restrict__ emb_w,
                         const int* __restrict__ dst,
                         unsigned short* __restrict__ WpF1, unsigned short* __restrict__ WpF2,
                         unsigned short* __restrict__ smPack, unsigned* __restrict__ emb_bf,
                         int* __restrict__ cnt) {
    __shared__ int lh[NBUCK];
    int t = threadIdx.x;
    if (blockIdx.x < NBLK_P) {
        int blk = blockIdx.x;
        for (int b = t; b < NBUCK; b += TPB_P) lh[b] = 0;
        __syncthreads();
        int base = blk * EPB;
        for (int i = t; i < EPB; i += TPB_P) atomicAdd(&lh[dst[base + i] >> B_SHIFT], 1);
        __syncthreads();
        for (int b = t; b < NBUCK; b += TPB_P) cnt[blk * NBUCK + b] = lh[b];
        return;
    }
    int idx = (blockIdx.x - NBLK_P) * 256 + t;
    if (idx < 65536) {
        int l = idx >> 15;
        int r = (idx >> 12) & 7;
        int k = (idx >> 6) & 63;
        int o = idx & 63;
        const float* V = l ? V2 : V1;
        const float* comp = l ? comp2 : comp1;
        float s = 0.f;
#pragma unroll
        for (int b = 0; b < 8; b++) s += comp[r * 8 + b] * V[(b * 64 + k) * 64 + o];
        int kk = r * 64 + k;
        int ss = kk >> 5, q = (kk >> 3) & 3, j = kk & 7;
        unsigned short* Wp = l ? WpF2 : WpF1;
        Wp[(((ss * 4 + q) * 64) + o) * 8 + j] = f2bf(s);
    } else if (idx < 81920) {
        int j = idx - 65536;
        int k = j >> 6, o = j & 63;
        int s = k >> 5, q = (k >> 3) & 3, jj = k & 7;
        smPack[(((s * 4 + q) * 64) + o) * 8 + jj] = f2bf(sm_w[o * KDIM + k]);
    } else {
        int j = idx - 81920;                 // pair index: 3.2M bf16 = 1.6M dwords
        if (j < 1600000) {
            const float2* f2p = (const float2*)emb_w;
            float2 f = f2p[j];
            emb_bf[j] = ((unsigned)f2bf(f.x)) | (((unsigned)f2bf(f.y)) << 16);
        }
    }
}

// ---------------- pass B1: per-bucket exclusive scan across the NBLK_P blocks
__launch_bounds__(NBLK_P)
__global__ void k_pscan(const int* __restrict__ cnt, int* __restrict__ boffm, int* __restrict__ btot) {
    __shared__ int s[NBLK_P];
    int b = blockIdx.x, t = threadIdx.x;
    int v = cnt[t * NBUCK + b];
    s[t] = v;
    __syncthreads();
    for (int off = 1; off < NBLK_P; off <<= 1) {
        int u = (t >= off) ? s[t - off] : 0;
        __syncthreads();
        s[t] += u;
        __syncthreads();
    }
    boffm[t * NBUCK + b] = s[t] - v;
    if (t == NBLK_P - 1) btot[b] = s[NBLK_P - 1];
}

// 256-thread recompute of bucket starts from btot (each thread owns 2 bins)
__device__ inline void bstart256(const int* __restrict__ btot, int* sB, int* bst) {
    int t = threadIdx.x;
    int i0 = t * 2, i1 = t * 2 + 1;
    int v0 = (i0 < NBUCK_USED) ? btot[i0] : 0;
    int v1 = (i1 < NBUCK_USED) ? btot[i1] : 0;
    int pv = v0 + v1;
    sB[t] = pv;
    __syncthreads();
    for (int off = 1; off < 256; off <<= 1) {
        int u = (t >= off) ? sB[t - off] : 0;
        __syncthreads();
        sB[t] += u;
        __syncthreads();
    }
    int excl = sB[t] - pv;
    if (i0 < NBUCK) bst[i0] = excl;
    if (i1 < NBUCK) bst[i1] = excl + v0;
    __syncthreads();
}

// ---------------- build2: pscatter (bucket-contiguous staging) ∥ sizematch
// blocks [0, NBLK_P): scatter edges; bucket starts recomputed from btot in LDS
// blocks [NBLK_P, NBLK_P+NBLK_SM): size matcher (MFMA, bf16 emb 64 B/row gathers)
__launch_bounds__(256)
__global__ void k_build2(const int* __restrict__ src, const int* __restrict__ dst,
                         const int* __restrict__ et, const float* __restrict__ norm,
                         const int* __restrict__ boffm, const int* __restrict__ btot,
                         int2* __restrict__ staged,
                         const int* __restrict__ feat, const unsigned* __restrict__ emb_bf,
                         const unsigned short* __restrict__ smPack, const float* __restrict__ sm_b,
                         unsigned short* __restrict__ xb) {
    __shared__ int sB[256];
    __shared__ int bst[NBUCK];
    __shared__ int ldsoff[NBUCK];
    int t = threadIdx.x;
    if (blockIdx.x < NBLK_P) {
        int blk = blockIdx.x;
        bstart256(btot, sB, bst);
        for (int b = t; b < NBUCK; b += TPB_P) ldsoff[b] = bst[b] + boffm[blk * NBUCK + b];
        __syncthreads();
        int base = blk * EPB;
        for (int i = t; i < EPB; i += TPB_P) {
            int e = base + i;
            int d = dst[e];
            int bu = d >> B_SHIFT;
            int pos = atomicAdd(&ldsoff[bu], 1);
            int packed = src[e] | (et[e] << 17) | ((d & 255) << 20);
            staged[pos] = make_int2(packed, __float_as_int(norm[e]));
        }
        return;
    }
    // ---- size matcher
    int wave = t >> 6, lane = t & 63;
    int q = lane >> 4, c = lane & 15;
    int n0 = (blockIdx.x - NBLK_P) * 64 + wave * 16;
    int node = n0 + c;
    int nclamp = (node < N_NODES) ? node : (N_NODES - 1);
    const int4* fr = (const int4*)(feat + (size_t)nclamp * 8);
    int4 f0 = fr[0], f1 = fr[1];
    int fidx[8] = {f0.x, f0.y, f0.z, f0.w, f1.x, f1.y, f1.z, f1.w};
    f32x4 acc[4];
#pragma unroll
    for (int i = 0; i < 4; i++) acc[i] = (f32x4){0.f, 0.f, 0.f, 0.f};
    const bf16x8* B8 = (const bf16x8*)smPack;
#pragma unroll
    for (int s = 0; s < 8; s++) {
        // row fidx[s] = 32 bf16 = 64 B; lane q takes elements q*8..q*8+7 (16 B)
        const int4* ar = (const int4*)((const char*)emb_bf + (size_t)fidx[s] * 64);
        union { int4 i; bf16x8 v; } A;
        A.i = ar[q];
#pragma unroll
        for (int tl = 0; tl < 4; tl++) {
            bf16x8 b = B8[(s * 4 + q) * 64 + tl * 16 + c];
            acc[tl] = __builtin_amdgcn_mfma_f32_16x16x32_bf16(A.v, b, acc[tl], 0, 0, 0);
        }
    }
    int row_base = n0 + q * 4;
    bool full = (n0 + 15 < N_NODES);
#pragma unroll
    for (int tl = 0; tl < 4; tl++) {
        int o = tl * 16 + c;
        float bia = sm_b[o];
#pragma unroll
        for (int r = 0; r < 4; r++) {
            int nd = row_base + r;
            if (full || nd < N_NODES)
                xb[(size_t)nd * 64 + o] = f2bf(acc[tl][r] + bia);
        }
    }
}

// ---------------- pass D: per-bucket 2048-bin counting sort -> rowptr8 + sorted edata
// bucket starts recomputed from btot (512-thread scan); sentinel written by blk 0
// edata stores x = (src<<7) | et  (byte offset of xin row in bits 7..23, rel in 0..2)
__launch_bounds__(512)
__global__ void k_finalize(const int2* __restrict__ staged, const int* __restrict__ btot,
                           int* __restrict__ rowptr8, int2* __restrict__ edata) {
    __shared__ int lh[2048];
    __shared__ int s512[512];
    __shared__ int lsc[2048];
    __shared__ int bst[512];
    int b = blockIdx.x, t = threadIdx.x;
    {   // recompute bucket starts (exclusive scan of btot over 391 buckets)
        int v = (t < NBUCK_USED) ? btot[t] : 0;
        s512[t] = v;
        __syncthreads();
        for (int off = 1; off < 512; off <<= 1) {
            int u = (t >= off) ? s512[t - off] : 0;
            __syncthreads();
            s512[t] += u;
            __syncthreads();
        }
        bst[t] = s512[t] - v;
        __syncthreads();
    }
    int base = bst[b];
    int cnt = btot[b];
    if (b == 0 && t == 0) rowptr8[(size_t)N_NODES * 8] = N_EDGES;
    lh[t] = 0; lh[t + 512] = 0; lh[t + 1024] = 0; lh[t + 1536] = 0;
    __syncthreads();
    int2 held[9];
    int key[9], rank[9];
    int nh = 0;
    for (int i = t; i < cnt; i += 512) {
        int2 ed = staged[base + i];
        int k = (ed.x >> 17) & 2047;
        held[nh] = ed; key[nh] = k; rank[nh] = atomicAdd(&lh[k], 1); nh++;
    }
    __syncthreads();
    int b0 = lh[t * 4], b1 = lh[t * 4 + 1], b2 = lh[t * 4 + 2], b3 = lh[t * 4 + 3];
    int tot = b0 + b1 + b2 + b3;
    s512[t] = tot;
    __syncthreads();
    for (int off = 1; off < 512; off <<= 1) {
        int u = (t >= off) ? s512[t - off] : 0;
        __syncthreads();
        s512[t] += u;
        __syncthreads();
    }
    int excl = s512[t] - tot;
    lsc[t * 4] = excl;
    lsc[t * 4 + 1] = excl + b0;
    lsc[t * 4 + 2] = excl + b0 + b1;
    lsc[t * 4 + 3] = excl + b0 + b1 + b2;
    __syncthreads();
    int limit = (N_NODES << 3) - (b << 11);
    for (int idx = t; idx < 2048; idx += 512)
        if (idx < limit) rowptr8[(b << 11) + idx] = base + lsc[idx];
    for (int i = 0; i < nh; i++) {
        int p = base + lsc[key[i]] + rank[i];
        int srcv = held[i].x & 0x1FFFF;
        int etv  = (held[i].x >> 17) & 7;
        edata[p] = make_int2((srcv << 7) | etv, held[i].y);   // byte-offset | et
    }
}

// ---------------- fused layer: branchless always-write aggregation + MFMA (R5/R8)
// block: 256 thr = 4 waves; 16 nodes/block (4 per wave); grid N_NODES/16.
// Edge descriptors via addrspace(4) scalar loads (s_load into SGPRs).
// Consume is BRANCHLESS: keep = (et==prev), acc = fma(y,w, acc*keep), and the
// running sum is stored to agg[row][et*64+lane] EVERY edge (shift-16 store).
// The last write of each rel segment leaves the final value.
// NOTE: no min-waves hint — forcing 8 blocks/CU (R9) raised occupancy 59->69%
// but thrashed L2 on the xin gathers (FETCH 93->109 MB) and cost +6.5 us.
__launch_bounds__(256)
__global__ void k_fused(const unsigned short* __restrict__ xin,
                        const int* __restrict__ rowptr8, const int2* __restrict__ edata,
                        const unsigned short* __restrict__ WpF, const float* __restrict__ bias,
                        float* __restrict__ outf, unsigned short* __restrict__ outb, int mode) {
    __shared__ __align__(16) unsigned short agg[16 * 520];
    int t = threadIdx.x;
    int wave = t >> 6, lane = t & 63;
    int n0 = blockIdx.x * 16;
    ep_cptr ep4 = (ep_cptr)(unsigned long long)edata;
    ci_cptr rp4 = (ci_cptr)(unsigned long long)rowptr8;
    // each wave zero-inits only its OWN 4 rows; it is also the only writer of
    // them during the edge phase, so no barrier is needed before the edge loop.
    {
        int* a4 = (int*)agg + wave * 4 * 260;
        for (int i = lane; i < 4 * 260; i += 64) a4[i] = 0;
    }
#define EF(S,k)  int x##S##k = ep4[j##S + (k)].x, y##S##k = ep4[j##S + (k)].y;
#define EFM(S,k) int q##S##k = j##S + (k); \
                 int c##S##k = (q##S##k <= last##S) ? q##S##k : last##S; \
                 c##S##k = (c##S##k < 0) ? 0 : c##S##k; \
                 int x##S##k = ep4[c##S##k].x; \
                 int y##S##k = (q##S##k <= last##S) ? ep4[c##S##k].y : 0;
#define GF(S,k)  unsigned short w##S##k = *((const unsigned short*)((const char*)xin + (x##S##k & 0x00FFFF80)) + lane);
#define CN(S,k)  { int et = x##S##k & 7; \
                   float keep = (et == prev##S) ? 1.0f : 0.0f; \
                   prev##S = et; \
                   acc##S = fmaf(__int_as_float(y##S##k), bf2f(w##S##k), acc##S * keep); \
                   unsigned bb = __float_as_uint(acc##S) + 0x8000u; \
                   aggrow##S[et * 64 + lane] = (unsigned short)(bb >> 16); }
#define EF8(S)   EF(S,0) EF(S,1) EF(S,2) EF(S,3) EF(S,4) EF(S,5) EF(S,6) EF(S,7)
#define EFM8(S)  EFM(S,0) EFM(S,1) EFM(S,2) EFM(S,3) EFM(S,4) EFM(S,5) EFM(S,6) EFM(S,7)
#define GF8(S)   GF(S,0) GF(S,1) GF(S,2) GF(S,3) GF(S,4) GF(S,5) GF(S,6) GF(S,7)
#define CN8(S)   CN(S,0) CN(S,1) CN(S,2) CN(S,3) CN(S,4) CN(S,5) CN(S,6) CN(S,7)
    for (int np = 0; np < 2; np++) {
        int lrowA = wave * 4 + np * 2;
        int lrowB = lrowA + 1;
        int nA = __builtin_amdgcn_readfirstlane(n0 + lrowA);
        int nB = nA + 1;
        int j0A = rp4[(size_t)nA * 8], j1A = rp4[(size_t)nA * 8 + 8];
        int j0B = rp4[(size_t)nB * 8], j1B = rp4[(size_t)nB * 8 + 8];
        unsigned short* aggrowA = agg + lrowA * 520;
        unsigned short* aggrowB = agg + lrowB * 520;
        float accA = 0.f, accB = 0.f;
        int prevA = -1, prevB = -1;
        int jA = j0A, jB = j0B;
        while (jA + 8 <= j1A && jB + 8 <= j1B) {
            EF8(A) EF8(B) GF8(A) GF8(B) CN8(A) CN8(B)
            jA += 8; jB += 8;
        }
        while (jA + 8 <= j1A) { EF8(A) GF8(A) CN8(A) jA += 8; }
        while (jB + 8 <= j1B) { EF8(B) GF8(B) CN8(B) jB += 8; }
        {
            int lastA = j1A - 1, lastB = j1B - 1;
            if (((j1A - jA) | (j1B - jB)) > 0) {
                EFM8(A) EFM8(B) GF8(A) GF8(B) CN8(A) CN8(B)
            }
        }
    }
#undef EF
#undef EFM
#undef GF
#undef CN
#undef EF8
#undef EFM8
#undef GF8
#undef CN8
    __syncthreads();
    // ---- MFMA: [16 nodes x 512] @ WpF -> 64 outs; wave covers cols [wave*16, +16)
    int q = lane >> 4, c = lane & 15;
    int o16 = wave * 16;
    f32x4 accd = (f32x4){0.f, 0.f, 0.f, 0.f};
    const bf16x8* B8 = (const bf16x8*)WpF;
#pragma unroll
    for (int s = 0; s < 16; s++) {
        bf16x8 a = *(const bf16x8*)&agg[c * 520 + s * 32 + q * 8];
        bf16x8 bfr = B8[(s * 4 + q) * 64 + o16 + c];
        accd = __builtin_amdgcn_mfma_f32_16x16x32_bf16(a, bfr, accd, 0, 0, 0);
    }
    int col = o16 + c;
    float bia = bias[col];
#pragma unroll
    for (int r = 0; r < 4; r++) {
        int node = n0 + q * 4 + r;
        float v = accd[r] + bia;
        if (mode == 1) {
            v = fmaxf(v, 0.f);
            outb[(size_t)node * 64 + col] = f2bf(v);
        } else {
            outf[(size_t)node * 64 + col] = v;
        }
    }
}

extern "C" void kernel_launch(void* const* d_in, const int* in_sizes, int n_in,
                              void* d_out, int out_size, void* d_ws, size_t ws_size,
                              hipStream_t stream) {
    const int*   feat  = (const int*)d_in[0];
    const int*   src   = (const int*)d_in[1];
    const int*   dst   = (const int*)d_in[2];
    const int*   etype = (const int*)d_in[3];
    const float* norm  = (const float*)d_in[4];
    const float* emb_w = (const float*)d_in[5];
    const float* sm_w  = (const float*)d_in[6];
    const float* sm_b  = (const float*)d_in[7];
    const float* V1    = (const float*)d_in[8];
    const float* comp1 = (const float*)d_in[9];
    const float* b1    = (const float*)d_in[10];
    const float* V2    = (const float*)d_in[11];
    const float* comp2 = (const float*)d_in[12];
    const float* b2    = (const float*)d_in[13];
    float* out = (float*)d_out;

    char* p = (char*)d_ws;
    auto alloc = [&](size_t bytes) { void* q = (void*)p; p += (bytes + 255) & ~(size_t)255; return q; };
    unsigned short* xb     = (unsigned short*)alloc((size_t)N_PAD * 64 * 2);   // 12.8 MB
    unsigned short* hb     = (unsigned short*)alloc((size_t)N_PAD * 64 * 2);   // 12.8 MB
    unsigned short* WpF1   = (unsigned short*)alloc((size_t)KF * HD * 2);      // 64 KB
    unsigned short* WpF2   = (unsigned short*)alloc((size_t)KF * HD * 2);
    unsigned short* smPack = (unsigned short*)alloc(KDIM * HD * 2);            // 32 KB
    unsigned*       emb_bf = (unsigned*)alloc((size_t)N_NODES * 32 * 2);       // 6.4 MB
    int*   cnt    = (int*)alloc((size_t)NBLK_P * NBUCK * 4);                   // 803 KB
    int*   boffm  = (int*)alloc((size_t)NBLK_P * NBUCK * 4);                   // 803 KB
    int*   btot   = (int*)alloc((size_t)NBUCK * 4);
    int*   rowptr8 = (int*)alloc(((size_t)N_NODES * 8 + 1) * 4);               // 3.2 MB
    int2*  staged = (int2*)alloc((size_t)N_EDGES * 8);                         // 12.8 MB
    int2*  edata  = (int2*)alloc((size_t)N_EDGES * 8);                         // 12.8 MB

    // build1: 512 pcount blocks + 6570 prep blocks
    k_build1<<<NBLK_P + 6570, 256, 0, stream>>>(V1, comp1, V2, comp2, sm_w, emb_w, dst,
                                                WpF1, WpF2, smPack, emb_bf, cnt);
    k_pscan<<<NBUCK_USED, NBLK_P, 0, stream>>>(cnt, boffm, btot);
    // build2: 512 pscatter blocks + 1563 sizematch blocks
    k_build2<<<NBLK_P + NBLK_SM, 256, 0, stream>>>(src, dst, etype, norm, boffm, btot, staged,
                                                   feat, emb_bf, smPack, sm_b, xb);
    k_finalize<<<NBUCK_USED, 512, 0, stream>>>(staged, btot, rowptr8, edata);

    k_fused<<<N_NODES / 16, 256, 0, stream>>>(xb, rowptr8, edata, WpF1, b1, nullptr, hb, 1);
    k_fused<<<N_NODES / 16, 256, 0, stream>>>(hb, rowptr8, edata, WpF2, b2, out, nullptr, 0);
}